// Round 5
// baseline (308.596 us; speedup 1.0000x reference)
//
#include <hip/hip_runtime.h>
#include <hip/hip_bf16.h>
#include <math.h>

#define N_NODES 50000
#define N_EDGES 600000
#define NFEAT   256
#define NHID    128
#define NCLASS  40

typedef __attribute__((ext_vector_type(8))) short bf16x8;
typedef __attribute__((ext_vector_type(4))) float f32x4;

__device__ inline ushort f2bf(float f) {   // RNE, finite inputs
    uint u = __float_as_uint(f);
    uint r = (u + 0x7fffu + ((u >> 16) & 1u)) >> 16;
    return (ushort)r;
}

// ---------------------------------------------------------------------------
// CSR build
__global__ __launch_bounds__(256) void hist_kernel(const int* __restrict__ dst,
                                                   int* __restrict__ cnt, int E) {
    int i = blockIdx.x * 256 + threadIdx.x;
    if (i < E) atomicAdd(&cnt[dst[i]], 1);
}

__global__ __launch_bounds__(256) void scan_bsum(const int* __restrict__ cnt,
                                                 int* __restrict__ bsum, int n) {
    __shared__ int red[4];
    int i = blockIdx.x * 256 + threadIdx.x;
    int v = (i < n) ? cnt[i] : 0;
    #pragma unroll
    for (int off = 32; off; off >>= 1) v += __shfl_down(v, off, 64);
    int wave = threadIdx.x >> 6, lane = threadIdx.x & 63;
    if (lane == 0) red[wave] = v;
    __syncthreads();
    if (threadIdx.x == 0) bsum[blockIdx.x] = red[0] + red[1] + red[2] + red[3];
}

__global__ __launch_bounds__(256) void scan_boff(int* __restrict__ bsum, int nb) {
    __shared__ int buf[256];
    int tid = threadIdx.x;
    int v = (tid < nb) ? bsum[tid] : 0;
    buf[tid] = v;
    __syncthreads();
    #pragma unroll
    for (int off = 1; off < 256; off <<= 1) {
        int t = (tid >= off) ? buf[tid - off] : 0;
        __syncthreads();
        buf[tid] += t;
        __syncthreads();
    }
    if (tid < nb) bsum[tid] = buf[tid] - v;
}

__global__ __launch_bounds__(256) void scan_final(const int* __restrict__ cnt,
                                                  const int* __restrict__ boff,
                                                  int* __restrict__ rs,
                                                  int* __restrict__ cur, int n) {
    __shared__ int buf[256];
    int tid = threadIdx.x;
    int i = blockIdx.x * 256 + tid;
    int v = (i < n) ? cnt[i] : 0;
    buf[tid] = v;
    __syncthreads();
    #pragma unroll
    for (int off = 1; off < 256; off <<= 1) {
        int t = (tid >= off) ? buf[tid - off] : 0;
        __syncthreads();
        buf[tid] += t;
        __syncthreads();
    }
    int ex = buf[tid] - v + boff[blockIdx.x];
    if (i < n) { rs[i] = ex; cur[i] = ex; }
    if (i == n - 1) rs[n] = ex + v;
}

// Scatter edges into dst-sorted order as packed int2{src, bits(w)} (ONE 8B
// store per edge -> halves random-write line-dirty events vs two arrays)
__global__ __launch_bounds__(256) void scatter_kernel(const int* __restrict__ src,
                                                      const int* __restrict__ dst,
                                                      const float* __restrict__ w,
                                                      int* __restrict__ cur,
                                                      int2* __restrict__ edges, int E) {
    int i = blockIdx.x * 256 + threadIdx.x;
    if (i >= E) return;
    int p = atomicAdd(&cur[dst[i]], 1);
    edges[p] = make_int2(src[i], __float_as_int(w[i]));
}

// ---------------------------------------------------------------------------
// Converters
__global__ __launch_bounds__(256) void cvt_bf16_vec(const float* __restrict__ in,
                                                    ushort* __restrict__ out, int n4) {
    int i = blockIdx.x * 256 + threadIdx.x;
    if (i >= n4) return;
    float4 v = *(const float4*)(in + (size_t)i * 4);
    ushort4 o;
    o.x = f2bf(v.x); o.y = f2bf(v.y); o.z = f2bf(v.z); o.w = f2bf(v.w);
    *(ushort4*)(out + (size_t)i * 4) = o;
}

// All three weight transposes in one launch.
// BT1: 128x256 from W1[256x128]; BT2: 128x128 from W2[128x128];
// BT3: 64x128 from W3[128x40] (rows>=40 zero).
__global__ __launch_bounds__(256) void cvt_w_all(const float* __restrict__ W1,
                                                 const float* __restrict__ W2,
                                                 const float* __restrict__ W3,
                                                 ushort* __restrict__ BT1,
                                                 ushort* __restrict__ BT2,
                                                 ushort* __restrict__ BT3) {
    int idx = blockIdx.x * 256 + threadIdx.x;
    if (idx < 32768) {                       // BT1
        int nr = idx >> 8, k = idx & 255;
        BT1[idx] = f2bf(W1[(size_t)k * 128 + nr]);
    } else if (idx < 49152) {                // BT2
        int t = idx - 32768;
        int nr = t >> 7, k = t & 127;
        BT2[t] = f2bf(W2[(size_t)k * 128 + nr]);
    } else if (idx < 57344) {                // BT3
        int t = idx - 49152;
        int nr = t >> 7, k = t & 127;
        BT3[t] = (nr < 40) ? f2bf(W3[(size_t)k * 40 + nr]) : (ushort)0;
    }
}

// ---------------------------------------------------------------------------
// bf16 MFMA GEMM: C[M x Nout] = A[M x K] @ BT[.. x K]^T
template<int NT, bool OUTBF>
__global__ __launch_bounds__(256) void gemm_mfma(const ushort* __restrict__ A,
                                                 const ushort* __restrict__ BT,
                                                 int M, int K, int Nout,
                                                 void* __restrict__ Cout) {
    __shared__ ushort a_s[64 * 40];
    __shared__ ushort b_s[64 * NT * 40];
    int tid = threadIdx.x;
    int row0 = blockIdx.x * 64;
    int wave = tid >> 6, lane = tid & 63;
    int lr = lane & 15, lk = (lane >> 4) * 8;
    f32x4 acc[4][NT];
    #pragma unroll
    for (int mt = 0; mt < 4; ++mt)
        #pragma unroll
        for (int nt = 0; nt < NT; ++nt) acc[mt][nt] = (f32x4){0.f, 0.f, 0.f, 0.f};

    for (int k0 = 0; k0 < K; k0 += 32) {
        {   // A tile: 64 rows x 32 k, one 16B chunk/thread
            int r = tid >> 2, c8 = (tid & 3) * 8;
            int gr = row0 + r; if (gr >= M) gr = M - 1;  // clamp, store-guarded
            float4 v = *(const float4*)(A + (size_t)gr * K + k0 + c8);
            *(float4*)(a_s + r * 40 + c8) = v;
        }
        #pragma unroll
        for (int i = 0; i < NT; ++i) {  // BT tile: 64*NT rows x 32 k
            int idx = tid * NT + i;
            int r = idx >> 2, c8 = (idx & 3) * 8;
            float4 v = *(const float4*)(BT + (size_t)r * K + k0 + c8);
            *(float4*)(b_s + r * 40 + c8) = v;
        }
        __syncthreads();
        bf16x8 bfr[NT];
        #pragma unroll
        for (int nt = 0; nt < NT; ++nt)
            bfr[nt] = *(const bf16x8*)(b_s + ((wave * NT + nt) * 16 + lr) * 40 + lk);
        #pragma unroll
        for (int mt = 0; mt < 4; ++mt) {
            bf16x8 afr = *(const bf16x8*)(a_s + (mt * 16 + lr) * 40 + lk);
            #pragma unroll
            for (int nt = 0; nt < NT; ++nt)
                acc[mt][nt] = __builtin_amdgcn_mfma_f32_16x16x32_bf16(
                    afr, bfr[nt], acc[mt][nt], 0, 0, 0);
        }
        __syncthreads();
    }
    // C/D layout: col = lane&15, row = (lane>>4)*4 + i
    int col0 = wave * NT * 16;
    #pragma unroll
    for (int mt = 0; mt < 4; ++mt) {
        int gr0 = row0 + mt * 16 + (lane >> 4) * 4;
        #pragma unroll
        for (int nt = 0; nt < NT; ++nt) {
            int gc = col0 + nt * 16 + lr;
            #pragma unroll
            for (int i = 0; i < 4; ++i) {
                int gr = gr0 + i;
                if (gr < M && gc < Nout) {
                    if (OUTBF)
                        ((ushort*)Cout)[(size_t)gr * Nout + gc] = f2bf(acc[mt][nt][i]);
                    else
                        ((float*)Cout)[(size_t)gr * Nout + gc] = acc[mt][nt][i];
                }
            }
        }
    }
}

// ---------------------------------------------------------------------------
// SpMM over bf16 support, 8-edge batched, packed int2 edge records.
__global__ __launch_bounds__(256) void spmm128b(const uint* __restrict__ sup,
                                                const int* __restrict__ rs,
                                                const int2* __restrict__ edges,
                                                const float* __restrict__ bias,
                                                uint* __restrict__ outb, int n) {
    int wid = blockIdx.x * 4 + (threadIdx.x >> 6);
    int lane = threadIdx.x & 63;
    if (wid >= n) return;
    int k = rs[wid], e = rs[wid + 1];
    float ax = 0.f, ay = 0.f;
    while (k < e) {
        int2 rec[8];
        #pragma unroll
        for (int j = 0; j < 8; ++j) {
            int kk = k + j;
            rec[j] = edges[(kk < e) ? kk : (e - 1)];
            if (kk >= e) rec[j].y = 0;  // zero weight on padding
        }
        uint p[8];
        #pragma unroll
        for (int j = 0; j < 8; ++j) p[j] = sup[(size_t)rec[j].x * 64 + lane];
        #pragma unroll
        for (int j = 0; j < 8; ++j) {
            float w = __int_as_float(rec[j].y);
            ax += __uint_as_float(p[j] << 16) * w;
            ay += __uint_as_float(p[j] & 0xffff0000u) * w;
        }
        k += 8;
    }
    ax = fmaxf(ax + bias[lane * 2], 0.f);
    ay = fmaxf(ay + bias[lane * 2 + 1], 0.f);
    outb[(size_t)wid * 64 + lane] = ((uint)f2bf(ay) << 16) | (uint)f2bf(ax);
}

// Layer 3: bf16 F=40 segment-sum + bias + log_softmax fused -> d_out (fp32)
__global__ __launch_bounds__(256) void spmm40_lsm(const ushort* __restrict__ sup,
                                                  const int* __restrict__ rs,
                                                  const int2* __restrict__ edges,
                                                  const float* __restrict__ bias,
                                                  float* __restrict__ out, int n) {
    int wid = blockIdx.x * 4 + (threadIdx.x >> 6);
    int lane = threadIdx.x & 63;
    if (wid >= n) return;
    int k = rs[wid], e = rs[wid + 1];
    float acc = 0.f;
    int lf = (lane < 40) ? lane : 39;  // inactive lanes read lane 39 (no OOB)
    while (k < e) {
        int2 rec[8];
        #pragma unroll
        for (int j = 0; j < 8; ++j) {
            int kk = k + j;
            rec[j] = edges[(kk < e) ? kk : (e - 1)];
            if (kk >= e) rec[j].y = 0;
        }
        float p[8];
        #pragma unroll
        for (int j = 0; j < 8; ++j) {
            uint us = sup[(size_t)rec[j].x * 40 + lf];
            p[j] = __uint_as_float(us << 16);
        }
        #pragma unroll
        for (int j = 0; j < 8; ++j) acc += p[j] * __int_as_float(rec[j].y);
        k += 8;
    }
    float v = (lane < 40) ? acc + bias[lane] : -INFINITY;
    float m = v;
    #pragma unroll
    for (int off = 32; off; off >>= 1) m = fmaxf(m, __shfl_xor(m, off, 64));
    float ex = (lane < 40) ? expf(v - m) : 0.f;
    float s = ex;
    #pragma unroll
    for (int off = 32; off; off >>= 1) s += __shfl_xor(s, off, 64);
    float ls = logf(s);
    if (lane < 40) out[(size_t)wid * 40 + lane] = v - m - ls;
}

// ---------------------------------------------------------------------------
extern "C" void kernel_launch(void* const* d_in, const int* in_sizes, int n_in,
                              void* d_out, int out_size, void* d_ws, size_t ws_size,
                              hipStream_t stream) {
    const float* x   = (const float*)d_in[0];
    const float* ew  = (const float*)d_in[1];
    const float* W1  = (const float*)d_in[2];
    const float* b1  = (const float*)d_in[3];
    const float* W2  = (const float*)d_in[4];
    const float* b2  = (const float*)d_in[5];
    const float* W3  = (const float*)d_in[6];
    const float* b3  = (const float*)d_in[7];
    const int* esrc  = (const int*)d_in[8];
    const int* edst  = (const int*)d_in[9];
    float* out = (float*)d_out;

    char* ws = (char*)d_ws;
    size_t off = 0;
    auto alloc = [&](size_t bytes) {
        size_t cur = off;
        off += (bytes + 255) & ~(size_t)255;
        return cur;
    };
    int* cnt     = (int*)(ws + alloc((N_NODES + 1) * sizeof(int)));
    int* rs      = (int*)(ws + alloc((N_NODES + 1) * sizeof(int)));
    int* cur     = (int*)(ws + alloc(N_NODES * sizeof(int)));   // reused for BTs
    int* bsum    = (int*)(ws + alloc(256 * sizeof(int)));
    int2* edges  = (int2*)(ws + alloc((size_t)N_EDGES * sizeof(int2)));
    char* Xreg   = ws + alloc((size_t)N_NODES * 256 * 2);       // 25.6 MB
    char* Sreg   = ws + alloc((size_t)N_NODES * 128 * 2);       // 12.8 MB
    char* Hreg   = ws + alloc((size_t)N_NODES * 128 * 2);       // 12.8 MB

    // cur (200 KB) is dead after scatter_kernel; BTs (112 KB) live there.
    ushort* BT1 = (ushort*)cur;                    // 128 x 256  (64 KB)
    ushort* BT2 = (ushort*)((char*)cur + 65536);   // 128 x 128  (32 KB)
    ushort* BT3 = (ushort*)((char*)cur + 98304);   // 64  x 128  (16 KB, rows>=40 zero)

    ushort* xb   = (ushort*)Xreg;                  // x as bf16 [N x 256]
    ushort* supA = (ushort*)Sreg;                  // gemm1 out
    ushort* hA   = (ushort*)Hreg;                  // spmm1 out
    ushort* supB = (ushort*)Xreg;                  // gemm2 out (xb dead)
    ushort* hB   = (ushort*)Sreg;                  // spmm2 out (supA dead)
    ushort* sup3 = (ushort*)(Xreg + 12800000);     // gemm3 out bf16 [N x 40]

    // --- CSR build (cur live here) ---
    hipMemsetAsync(cnt, 0, (N_NODES + 1) * sizeof(int), stream);
    hist_kernel<<<(N_EDGES + 255) / 256, 256, 0, stream>>>(edst, cnt, N_EDGES);
    int scan_blocks = (N_NODES + 255) / 256;  // 196
    scan_bsum<<<scan_blocks, 256, 0, stream>>>(cnt, bsum, N_NODES);
    scan_boff<<<1, 256, 0, stream>>>(bsum, scan_blocks);
    scan_final<<<scan_blocks, 256, 0, stream>>>(cnt, bsum, rs, cur, N_NODES);
    scatter_kernel<<<(N_EDGES + 255) / 256, 256, 0, stream>>>(esrc, edst, ew, cur,
                                                              edges, N_EDGES);

    // --- conversions (cur now dead -> BTs) ---
    cvt_bf16_vec<<<(N_NODES * 256 / 4 + 255) / 256, 256, 0, stream>>>(x, xb,
                                                                      N_NODES * 64);
    cvt_w_all<<<(57344 + 255) / 256, 256, 0, stream>>>(W1, W2, W3, BT1, BT2, BT3);

    int gemm_blocks = (N_NODES + 63) / 64;   // 782
    int spmm_blocks = (N_NODES + 3) / 4;     // 12500

    // --- layer 1 ---
    gemm_mfma<2, true><<<gemm_blocks, 256, 0, stream>>>(xb, BT1, N_NODES, 256, 128,
                                                        supA);
    spmm128b<<<spmm_blocks, 256, 0, stream>>>((const uint*)supA, rs, edges, b1,
                                              (uint*)hA, N_NODES);
    // --- layer 2 ---
    gemm_mfma<2, true><<<gemm_blocks, 256, 0, stream>>>(hA, BT2, N_NODES, 128, 128,
                                                        supB);
    spmm128b<<<spmm_blocks, 256, 0, stream>>>((const uint*)supB, rs, edges, b2,
                                              (uint*)hB, N_NODES);
    // --- layer 3 ---
    gemm_mfma<1, true><<<gemm_blocks, 256, 0, stream>>>(hB, BT3, N_NODES, 128, 40,
                                                        sup3);
    spmm40_lsm<<<spmm_blocks, 256, 0, stream>>>(sup3, rs, edges, b3, out, N_NODES);
}